// Round 18
// baseline (125.634 us; speedup 1.0000x reference)
//
#include <hip/hip_runtime.h>

// InterNet B=32,N=16,D=64,P=8. Factorized: conv(mask*[y1;y2],W_rel) =
// mask*(convA(x[o1]) + convB(x[o2])). 3 dispatches, no inter-block sync.
//   prep_w: weights -> bf16 Wt [tap][oc][ic]  (tiny)
//   k1: per image: stage x fp32 -> LDS bf16; relA/relB convs -> cA/cB bf16
//   k2: per image: stage x -> LDS; self conv -> xs(LDS fp32);
//       burst combine: 2 passes x 8 elems/thread, 30 uint4 loads in flight
//       (R15 had 4x4; R17's pipelined variant regressed and is reverted) ->
//       pred(LDS) -> aff conv -> a(LDS[a|x]) -> agg conv(128ic) -> out.

#define NIMG 512
#define IMGSZ 4096

using bf16x8 = __attribute__((ext_vector_type(8))) short;
using f32x4  = __attribute__((ext_vector_type(4))) float;
using u16x8  = __attribute__((ext_vector_type(8))) unsigned short;

__device__ inline unsigned short f2bf(float f) {
  union { float f; unsigned u; } v; v.f = f;
  unsigned r = v.u + 0x7fffu + ((v.u >> 16) & 1u);
  return (unsigned short)(r >> 16);
}

__device__ inline float bf_hi(unsigned u) {   // upper bf16 of dword
  union { unsigned u; float f; } c; c.u = u & 0xffff0000u; return c.f;
}
__device__ inline float bf_lo(unsigned u) {   // lower bf16 of dword
  union { unsigned u; float f; } c; c.u = (u & 0xffffu) << 16; return c.f;
}

// Wt slots: self [9][64][64] @0, aff @36864, rel [9][64][128] @73728,
//           agg [9][64][128] @147456.
__global__ __launch_bounds__(256) void prep_w(
    const float* __restrict__ Wr, const float* __restrict__ Ws,
    const float* __restrict__ Wa, const float* __restrict__ Wg,
    unsigned short* __restrict__ Wt)
{
  int idx = blockIdx.x * 256 + threadIdx.x;
  if (idx >= 221184) return;
  float v;
  if (idx < 73728) {
    int c = idx / 36864, r = idx % 36864;
    int t = r >> 12, oc = (r >> 6) & 63, ic = r & 63;
    v = (c == 0 ? Ws : Wa)[oc * 576 + ic * 9 + t];
  } else {
    int r2 = idx - 73728;
    int half = r2 / 73728, rr = r2 % 73728;
    int t = rr >> 13, oc = (rr >> 7) & 63, ic = rr & 127;
    v = (half ? Wg : Wr)[oc * 1152 + ic * 9 + t];
  }
  Wt[idx] = f2bf(v);
}

// batch b pinned to XCD b&7 (perf heuristic; correctness never depends on it)
__device__ inline void decode_img(int j, int& b, int& o) {
  b = ((j >> 7) << 3) | (j & 7);
  o = (j >> 3) & 15;
}

// stage x (fp32 [ic][px]) -> LDS bf16 [px][stride ROWX], cols at +coff.
template<int ROWX>
__device__ inline void stage_x(const float* __restrict__ xb,
                               unsigned short* __restrict__ s,
                               int coff, int w, int px) {
#pragma unroll
  for (int r = 0; r < 8; ++r) {
    int ic0 = (w + 4 * r) * 2;
    const float* sp = xb + ic0 * 64;
    float a = sp[px], c = sp[64 + px];
    *(unsigned*)(s + px * ROWX + coff + ic0) =
        (unsigned)f2bf(a) | ((unsigned)f2bf(c) << 16);
  }
}

__global__ __launch_bounds__(256) void k1(
    const float* __restrict__ x,
    const unsigned short* __restrict__ Wt,
    unsigned short* __restrict__ cA, unsigned short* __restrict__ cB)
{
  constexpr int ROW = 72;
  __shared__ __align__(16) unsigned short sX[65 * ROW];
  int b, o;
  decode_img(blockIdx.x, b, o);
  const int img = b * 16 + o;
  const int tid = threadIdx.x;
  const int w = tid >> 6, lane = tid & 63;

  stage_x<ROW>(x + (size_t)img * IMGSZ, sX, 0, w, lane);
  if (tid < 36) ((unsigned*)(sX + 64 * ROW))[tid] = 0;
  __syncthreads();

  const int q = lane >> 4, n16 = lane & 15;
  const int ocb = w * 16;
  const int co = ocb + q * 4;

  int pyt[4], pxt[4];
#pragma unroll
  for (int t = 0; t < 4; ++t) { int p = t * 16 + n16; pyt[t] = p >> 3; pxt[t] = p & 7; }

  f32x4 aA[4] = {}, aB[4] = {};
  const unsigned short* WA = Wt + 73728 + (ocb + n16) * 128 + q * 8;  // rel ic 0..63
  const unsigned short* WB = WA + 64;                                 // rel ic 64..127
#pragma unroll
  for (int tap = 0; tap < 9; ++tap) {
    const int dy = tap / 3 - 1, dx = tap % 3 - 1;
    int spt[4];
#pragma unroll
    for (int t = 0; t < 4; ++t) {
      int sy = pyt[t] + dy, sx = pxt[t] + dx;
      spt[t] = ((unsigned)sy < 8u && (unsigned)sx < 8u) ? (sy * 8 + sx) : 64;
    }
#pragma unroll
    for (int ks = 0; ks < 2; ++ks) {
      bf16x8 aa = *(const bf16x8*)(WA + tap * 8192 + ks * 32);
      bf16x8 ab = *(const bf16x8*)(WB + tap * 8192 + ks * 32);
#pragma unroll
      for (int t = 0; t < 4; ++t) {
        bf16x8 bt = *(const bf16x8*)(sX + spt[t] * ROW + ks * 32 + q * 8);
        aA[t] = __builtin_amdgcn_mfma_f32_16x16x32_bf16(aa, bt, aA[t], 0, 0, 0);
        aB[t] = __builtin_amdgcn_mfma_f32_16x16x32_bf16(ab, bt, aB[t], 0, 0, 0);
      }
    }
  }

  const size_t ib = (size_t)img * IMGSZ;
#pragma unroll
  for (int t = 0; t < 4; ++t) {
    int p = t * 16 + n16;
    uint2 pa, pb;
    pa.x = (unsigned)f2bf(aA[t][0]) | ((unsigned)f2bf(aA[t][1]) << 16);
    pa.y = (unsigned)f2bf(aA[t][2]) | ((unsigned)f2bf(aA[t][3]) << 16);
    pb.x = (unsigned)f2bf(aB[t][0]) | ((unsigned)f2bf(aB[t][1]) << 16);
    pb.y = (unsigned)f2bf(aB[t][2]) | ((unsigned)f2bf(aB[t][3]) << 16);
    *(uint2*)(cA + ib + p * 64 + co) = pa;
    *(uint2*)(cB + ib + p * 64 + co) = pb;
  }
}

__global__ __launch_bounds__(256, 2) void k2(
    const float* __restrict__ x,
    const int* __restrict__ g_idx,
    const unsigned short* __restrict__ Wt,
    const float* __restrict__ b_rel, const float* __restrict__ b_self,
    const float* __restrict__ b_aff, const float* __restrict__ b_agg,
    const unsigned short* __restrict__ cA, const unsigned short* __restrict__ cB,
    float* __restrict__ out)
{
  constexpr int ROW = 72, ROW2 = 136, XROW = 68;
  __shared__ __align__(16) unsigned short sX[65 * ROW2];   // [a | x] bf16
  __shared__ __align__(16) unsigned short sPred[65 * ROW]; // pred bf16
  __shared__ __align__(16) float sXS[64 * XROW];           // xs fp32
  __shared__ int so1[15], so2[15];
  __shared__ float sm[15];

  int b, i;
  decode_img(blockIdx.x, b, i);
  const int img = b * 16 + i;
  const int tid = threadIdx.x;
  const int w = tid >> 6, lane = tid & 63;

  if (tid < 15) {
    const int* gp = g_idx + ((size_t)b * 240 + i * 15 + tid) * 3;
    so1[tid] = gp[0] & 15;   // tile(x, n-1): x1[j] = x[j % 16]
    so2[tid] = gp[1] & 15;
    sm[tid]  = (float)gp[2];
  }

  stage_x<ROW2>(x + (size_t)img * IMGSZ, sX, 64, w, lane);
  if (tid < 68) ((unsigned*)(sX + 64 * ROW2))[tid] = 0;
  if (tid < 36) ((unsigned*)(sPred + 64 * ROW))[tid] = 0;
  __syncthreads();

  const int q = lane >> 4, n16 = lane & 15;
  const int ocb = w * 16;
  const int co = ocb + q * 4;
  const int aw64  = (ocb + n16) * 64 + q * 8;
  const int aw128 = (ocb + n16) * 128 + q * 8;

  int pyt[4], pxt[4];
#pragma unroll
  for (int t = 0; t < 4; ++t) { int p = t * 16 + n16; pyt[t] = p >> 3; pxt[t] = p & 7; }

  // ---- self conv (from staged x) -> xs in LDS fp32
  {
    f32x4 f[4] = {};
    const unsigned short* WS = Wt + aw64;
#pragma unroll
    for (int tap = 0; tap < 9; ++tap) {
      const int dy = tap / 3 - 1, dx = tap % 3 - 1;
      int spt[4];
#pragma unroll
      for (int t = 0; t < 4; ++t) {
        int sy = pyt[t] + dy, sx = pxt[t] + dx;
        spt[t] = ((unsigned)sy < 8u && (unsigned)sx < 8u) ? (sy * 8 + sx) : 64;
      }
#pragma unroll
      for (int ks = 0; ks < 2; ++ks) {
        bf16x8 a = *(const bf16x8*)(WS + tap * 4096 + ks * 32);
#pragma unroll
        for (int t = 0; t < 4; ++t) {
          bf16x8 bt = *(const bf16x8*)(sX + spt[t] * ROW2 + 64 + ks * 32 + q * 8);
          f[t] = __builtin_amdgcn_mfma_f32_16x16x32_bf16(a, bt, f[t], 0, 0, 0);
        }
      }
    }
#pragma unroll
    for (int t = 0; t < 4; ++t) {
      int p = t * 16 + n16;
      f32x4 vs = f[t];
#pragma unroll
      for (int r = 0; r < 4; ++r) vs[r] = fmaxf(vs[r] + b_self[co + r], 0.f);
      *(f32x4*)(sXS + p * XROW + co) = vs;
    }
  }
  __syncthreads();

  // ---- combine: pred = xs + sum_j relu(m_j*(cA[o1_j]+cB[o2_j]) + br)
  // 2 passes x 8 elems/thread; 30 uint4 (bf16x8) loads in flight per pass.
  {
    const size_t bb = (size_t)b * 16 * IMGSZ;
    const int e_ic = (tid & 7) * 8;       // pass-invariant
    float br[8];
#pragma unroll
    for (int r = 0; r < 8; ++r) br[r] = b_rel[e_ic + r];
#pragma unroll 1
    for (int pass = 0; pass < 2; ++pass) {
      const int e = tid * 8 + pass * 2048;   // 8 consecutive [px][ic] elems
      const int e_px = (tid >> 3) + pass * 32;
      uint4 v1[15], v2[15];
#pragma unroll
      for (int j = 0; j < 15; ++j) {
        v1[j] = *(const uint4*)(cA + bb + (size_t)so1[j] * IMGSZ + e);
        v2[j] = *(const uint4*)(cB + bb + (size_t)so2[j] * IMGSZ + e);
      }
      float acc[8];
      {
        const float* xp = sXS + e_px * XROW + e_ic;
#pragma unroll
        for (int r = 0; r < 8; ++r) acc[r] = xp[r];
      }
#pragma unroll
      for (int j = 0; j < 15; ++j) {
        float m = sm[j];
        float a1[8], a2[8];
        a1[0] = bf_lo(v1[j].x); a1[1] = bf_hi(v1[j].x);
        a1[2] = bf_lo(v1[j].y); a1[3] = bf_hi(v1[j].y);
        a1[4] = bf_lo(v1[j].z); a1[5] = bf_hi(v1[j].z);
        a1[6] = bf_lo(v1[j].w); a1[7] = bf_hi(v1[j].w);
        a2[0] = bf_lo(v2[j].x); a2[1] = bf_hi(v2[j].x);
        a2[2] = bf_lo(v2[j].y); a2[3] = bf_hi(v2[j].y);
        a2[4] = bf_lo(v2[j].z); a2[5] = bf_hi(v2[j].z);
        a2[6] = bf_lo(v2[j].w); a2[7] = bf_hi(v2[j].w);
#pragma unroll
        for (int r = 0; r < 8; ++r)
          acc[r] += fmaxf(m * (a1[r] + a2[r]) + br[r], 0.f);
      }
      u16x8 pk;
#pragma unroll
      for (int r = 0; r < 8; ++r) pk[r] = f2bf(acc[r]);
      *(u16x8*)(sPred + e_px * ROW + e_ic) = pk;
    }
  }
  __syncthreads();

  // ---- aff conv: sPred -> a -> sX cols 0..63
  {
    f32x4 f[4] = {};
    const unsigned short* WA = Wt + 36864 + aw64;
#pragma unroll
    for (int tap = 0; tap < 9; ++tap) {
      const int dy = tap / 3 - 1, dx = tap % 3 - 1;
      int spt[4];
#pragma unroll
      for (int t = 0; t < 4; ++t) {
        int sy = pyt[t] + dy, sx = pxt[t] + dx;
        spt[t] = ((unsigned)sy < 8u && (unsigned)sx < 8u) ? (sy * 8 + sx) : 64;
      }
#pragma unroll
      for (int ks = 0; ks < 2; ++ks) {
        bf16x8 a = *(const bf16x8*)(WA + tap * 4096 + ks * 32);
#pragma unroll
        for (int t = 0; t < 4; ++t) {
          bf16x8 bt = *(const bf16x8*)(sPred + spt[t] * ROW + ks * 32 + q * 8);
          f[t] = __builtin_amdgcn_mfma_f32_16x16x32_bf16(a, bt, f[t], 0, 0, 0);
        }
      }
    }
#pragma unroll
    for (int t = 0; t < 4; ++t) {
      int p = t * 16 + n16;
      float v0 = fmaxf(f[t][0] + b_aff[co + 0], 0.f);
      float v1 = fmaxf(f[t][1] + b_aff[co + 1], 0.f);
      float v2 = fmaxf(f[t][2] + b_aff[co + 2], 0.f);
      float v3 = fmaxf(f[t][3] + b_aff[co + 3], 0.f);
      uint2 pk;
      pk.x = (unsigned)f2bf(v0) | ((unsigned)f2bf(v1) << 16);
      pk.y = (unsigned)f2bf(v2) | ((unsigned)f2bf(v3) << 16);
      *(uint2*)(sX + p * ROW2 + co) = pk;
    }
  }
  __syncthreads();

  // ---- agg conv: sX (128 ic: [a|x]) -> out fp32 [ic][px]
  {
    f32x4 g[4] = {};
    const unsigned short* WG = Wt + 147456 + aw128;
#pragma unroll
    for (int tap = 0; tap < 9; ++tap) {
      const int dy = tap / 3 - 1, dx = tap % 3 - 1;
      int spt[4];
#pragma unroll
      for (int t = 0; t < 4; ++t) {
        int sy = pyt[t] + dy, sx = pxt[t] + dx;
        spt[t] = ((unsigned)sy < 8u && (unsigned)sx < 8u) ? (sy * 8 + sx) : 64;
      }
#pragma unroll
      for (int ks = 0; ks < 4; ++ks) {
        bf16x8 a = *(const bf16x8*)(WG + tap * 8192 + ks * 32);
#pragma unroll
        for (int t = 0; t < 4; ++t) {
          bf16x8 bt = *(const bf16x8*)(sX + spt[t] * ROW2 + ks * 32 + q * 8);
          g[t] = __builtin_amdgcn_mfma_f32_16x16x32_bf16(a, bt, g[t], 0, 0, 0);
        }
      }
    }
    float* ob = out + (size_t)img * IMGSZ;
#pragma unroll
    for (int t = 0; t < 4; ++t) {
      int p = t * 16 + n16;
#pragma unroll
      for (int r = 0; r < 4; ++r)
        ob[(co + r) * 64 + p] = fmaxf(g[t][r] + b_agg[co + r], 0.f);
    }
  }
}

extern "C" void kernel_launch(void* const* d_in, const int* in_sizes, int n_in,
                              void* d_out, int out_size, void* d_ws, size_t ws_size,
                              hipStream_t stream) {
  const float* x      = (const float*)d_in[0];
  const int*   g_idx  = (const int*)  d_in[1];
  const float* W_rel  = (const float*)d_in[2];
  const float* b_rel  = (const float*)d_in[3];
  const float* W_self = (const float*)d_in[4];
  const float* b_self = (const float*)d_in[5];
  const float* W_aff  = (const float*)d_in[6];
  const float* b_aff  = (const float*)d_in[7];
  const float* W_agg  = (const float*)d_in[8];
  const float* b_agg  = (const float*)d_in[9];
  float* out = (float*)d_out;

  unsigned short* cA = (unsigned short*)d_ws;      // [512][64][64] bf16
  unsigned short* cB = cA + 2097152;
  unsigned short* Wt = cB + 2097152;               // 221184 bf16

  prep_w<<<864, 256, 0, stream>>>(W_rel, W_self, W_aff, W_agg, Wt);
  k1<<<NIMG, 256, 0, stream>>>(x, Wt, cA, cB);
  k2<<<NIMG, 256, 0, stream>>>(x, g_idx, Wt, b_rel, b_self, b_aff, b_agg,
                               cA, cB, out);
}

// Round 19
// 118.368 us; speedup vs baseline: 1.0614x; 1.0614x over previous
//
#include <hip/hip_runtime.h>

// InterNet B=32,N=16,D=64,P=8. Factorized: conv(mask*[y1;y2],W_rel) =
// mask*(convA(x[o1]) + convB(x[o2])). 3 dispatches, no inter-block sync.
//   prep_w: weights -> bf16 Wt [tap][oc][ic]  (tiny)
//   k1: per image: stage x fp32 -> LDS bf16; relA/relB convs -> cA/cB bf16
//   k2: per image: stage x -> LDS; self conv -> xs (LDS, fp32);
//       burst combine (15 static pairs, 30 uint2 loads in flight/pass,
//       4 passes x 4 elems -- R15 shape, best measured) -> pred(LDS) ->
//       aff conv -> a(LDS[a|x]) -> agg conv(128ic) -> out
// R17 (pipelined combine) and R18 (2x8 uint4 combine) both regressed;
// this is the R15-proven optimum of the structure.

#define NIMG 512
#define IMGSZ 4096

using bf16x8 = __attribute__((ext_vector_type(8))) short;
using f32x4  = __attribute__((ext_vector_type(4))) float;
using u16x8  = __attribute__((ext_vector_type(8))) unsigned short;

__device__ inline unsigned short f2bf(float f) {
  union { float f; unsigned u; } v; v.f = f;
  unsigned r = v.u + 0x7fffu + ((v.u >> 16) & 1u);
  return (unsigned short)(r >> 16);
}

__device__ inline f32x4 bf4_to_f32(uint2 p) {
  union { unsigned u; float f; } c;
  f32x4 r;
  c.u = (p.x & 0xffffu) << 16;  r[0] = c.f;
  c.u = (p.x & 0xffff0000u);    r[1] = c.f;
  c.u = (p.y & 0xffffu) << 16;  r[2] = c.f;
  c.u = (p.y & 0xffff0000u);    r[3] = c.f;
  return r;
}

// Wt slots: self [9][64][64] @0, aff @36864, rel [9][64][128] @73728,
//           agg [9][64][128] @147456.
__global__ __launch_bounds__(256) void prep_w(
    const float* __restrict__ Wr, const float* __restrict__ Ws,
    const float* __restrict__ Wa, const float* __restrict__ Wg,
    unsigned short* __restrict__ Wt)
{
  int idx = blockIdx.x * 256 + threadIdx.x;
  if (idx >= 221184) return;
  float v;
  if (idx < 73728) {
    int c = idx / 36864, r = idx % 36864;
    int t = r >> 12, oc = (r >> 6) & 63, ic = r & 63;
    v = (c == 0 ? Ws : Wa)[oc * 576 + ic * 9 + t];
  } else {
    int r2 = idx - 73728;
    int half = r2 / 73728, rr = r2 % 73728;
    int t = rr >> 13, oc = (rr >> 7) & 63, ic = rr & 127;
    v = (half ? Wg : Wr)[oc * 1152 + ic * 9 + t];
  }
  Wt[idx] = f2bf(v);
}

// batch b pinned to XCD b&7 (perf heuristic; correctness never depends on it)
__device__ inline void decode_img(int j, int& b, int& o) {
  b = ((j >> 7) << 3) | (j & 7);
  o = (j >> 3) & 15;
}

// stage x (fp32 [ic][px]) -> LDS bf16 [px][stride ROWX], cols at +coff.
template<int ROWX>
__device__ inline void stage_x(const float* __restrict__ xb,
                               unsigned short* __restrict__ s,
                               int coff, int w, int px) {
#pragma unroll
  for (int r = 0; r < 8; ++r) {
    int ic0 = (w + 4 * r) * 2;
    const float* sp = xb + ic0 * 64;
    float a = sp[px], c = sp[64 + px];
    *(unsigned*)(s + px * ROWX + coff + ic0) =
        (unsigned)f2bf(a) | ((unsigned)f2bf(c) << 16);
  }
}

__global__ __launch_bounds__(256) void k1(
    const float* __restrict__ x,
    const unsigned short* __restrict__ Wt,
    unsigned short* __restrict__ cA, unsigned short* __restrict__ cB)
{
  constexpr int ROW = 72;
  __shared__ __align__(16) unsigned short sX[65 * ROW];
  int b, o;
  decode_img(blockIdx.x, b, o);
  const int img = b * 16 + o;
  const int tid = threadIdx.x;
  const int w = tid >> 6, lane = tid & 63;

  stage_x<ROW>(x + (size_t)img * IMGSZ, sX, 0, w, lane);
  if (tid < 36) ((unsigned*)(sX + 64 * ROW))[tid] = 0;
  __syncthreads();

  const int q = lane >> 4, n16 = lane & 15;
  const int ocb = w * 16;
  const int co = ocb + q * 4;

  int pyt[4], pxt[4];
#pragma unroll
  for (int t = 0; t < 4; ++t) { int p = t * 16 + n16; pyt[t] = p >> 3; pxt[t] = p & 7; }

  f32x4 aA[4] = {}, aB[4] = {};
  const unsigned short* WA = Wt + 73728 + (ocb + n16) * 128 + q * 8;  // rel ic 0..63
  const unsigned short* WB = WA + 64;                                 // rel ic 64..127
#pragma unroll
  for (int tap = 0; tap < 9; ++tap) {
    const int dy = tap / 3 - 1, dx = tap % 3 - 1;
    int spt[4];
#pragma unroll
    for (int t = 0; t < 4; ++t) {
      int sy = pyt[t] + dy, sx = pxt[t] + dx;
      spt[t] = ((unsigned)sy < 8u && (unsigned)sx < 8u) ? (sy * 8 + sx) : 64;
    }
#pragma unroll
    for (int ks = 0; ks < 2; ++ks) {
      bf16x8 aa = *(const bf16x8*)(WA + tap * 8192 + ks * 32);
      bf16x8 ab = *(const bf16x8*)(WB + tap * 8192 + ks * 32);
#pragma unroll
      for (int t = 0; t < 4; ++t) {
        bf16x8 bt = *(const bf16x8*)(sX + spt[t] * ROW + ks * 32 + q * 8);
        aA[t] = __builtin_amdgcn_mfma_f32_16x16x32_bf16(aa, bt, aA[t], 0, 0, 0);
        aB[t] = __builtin_amdgcn_mfma_f32_16x16x32_bf16(ab, bt, aB[t], 0, 0, 0);
      }
    }
  }

  const size_t ib = (size_t)img * IMGSZ;
#pragma unroll
  for (int t = 0; t < 4; ++t) {
    int p = t * 16 + n16;
    uint2 pa, pb;
    pa.x = (unsigned)f2bf(aA[t][0]) | ((unsigned)f2bf(aA[t][1]) << 16);
    pa.y = (unsigned)f2bf(aA[t][2]) | ((unsigned)f2bf(aA[t][3]) << 16);
    pb.x = (unsigned)f2bf(aB[t][0]) | ((unsigned)f2bf(aB[t][1]) << 16);
    pb.y = (unsigned)f2bf(aB[t][2]) | ((unsigned)f2bf(aB[t][3]) << 16);
    *(uint2*)(cA + ib + p * 64 + co) = pa;
    *(uint2*)(cB + ib + p * 64 + co) = pb;
  }
}

__global__ __launch_bounds__(256, 2) void k2(
    const float* __restrict__ x,
    const int* __restrict__ g_idx,
    const unsigned short* __restrict__ Wt,
    const float* __restrict__ b_rel, const float* __restrict__ b_self,
    const float* __restrict__ b_aff, const float* __restrict__ b_agg,
    const unsigned short* __restrict__ cA, const unsigned short* __restrict__ cB,
    float* __restrict__ out)
{
  constexpr int ROW = 72, ROW2 = 136, XROW = 68;
  __shared__ __align__(16) unsigned short sX[65 * ROW2];   // [a | x] bf16
  __shared__ __align__(16) unsigned short sPred[65 * ROW]; // pred bf16
  __shared__ __align__(16) float sXS[64 * XROW];           // xs fp32
  __shared__ int so1[15], so2[15];
  __shared__ float sm[15];

  int b, i;
  decode_img(blockIdx.x, b, i);
  const int img = b * 16 + i;
  const int tid = threadIdx.x;
  const int w = tid >> 6, lane = tid & 63;

  if (tid < 15) {
    const int* gp = g_idx + ((size_t)b * 240 + i * 15 + tid) * 3;
    so1[tid] = gp[0] & 15;   // tile(x, n-1): x1[j] = x[j % 16]
    so2[tid] = gp[1] & 15;
    sm[tid]  = (float)gp[2];
  }

  stage_x<ROW2>(x + (size_t)img * IMGSZ, sX, 64, w, lane);
  if (tid < 68) ((unsigned*)(sX + 64 * ROW2))[tid] = 0;
  if (tid < 36) ((unsigned*)(sPred + 64 * ROW))[tid] = 0;
  __syncthreads();

  const int q = lane >> 4, n16 = lane & 15;
  const int ocb = w * 16;
  const int co = ocb + q * 4;
  const int aw64  = (ocb + n16) * 64 + q * 8;
  const int aw128 = (ocb + n16) * 128 + q * 8;

  int pyt[4], pxt[4];
#pragma unroll
  for (int t = 0; t < 4; ++t) { int p = t * 16 + n16; pyt[t] = p >> 3; pxt[t] = p & 7; }

  // ---- self conv (from staged x) -> xs in LDS fp32
  {
    f32x4 f[4] = {};
    const unsigned short* WS = Wt + aw64;
#pragma unroll
    for (int tap = 0; tap < 9; ++tap) {
      const int dy = tap / 3 - 1, dx = tap % 3 - 1;
      int spt[4];
#pragma unroll
      for (int t = 0; t < 4; ++t) {
        int sy = pyt[t] + dy, sx = pxt[t] + dx;
        spt[t] = ((unsigned)sy < 8u && (unsigned)sx < 8u) ? (sy * 8 + sx) : 64;
      }
#pragma unroll
      for (int ks = 0; ks < 2; ++ks) {
        bf16x8 a = *(const bf16x8*)(WS + tap * 4096 + ks * 32);
#pragma unroll
        for (int t = 0; t < 4; ++t) {
          bf16x8 bt = *(const bf16x8*)(sX + spt[t] * ROW2 + 64 + ks * 32 + q * 8);
          f[t] = __builtin_amdgcn_mfma_f32_16x16x32_bf16(a, bt, f[t], 0, 0, 0);
        }
      }
    }
#pragma unroll
    for (int t = 0; t < 4; ++t) {
      int p = t * 16 + n16;
      f32x4 vs = f[t];
#pragma unroll
      for (int r = 0; r < 4; ++r) vs[r] = fmaxf(vs[r] + b_self[co + r], 0.f);
      *(f32x4*)(sXS + p * XROW + co) = vs;
    }
  }
  __syncthreads();

  // ---- combine: pred = xs + sum_j relu(m_j*(cA[o1_j]+cB[o2_j]) + br)
  // 4 passes x 4 elems/thread; 30 uint2 (bf16x4) loads in flight per pass.
  {
    const size_t bb = (size_t)b * 16 * IMGSZ;
#pragma unroll 1
    for (int pass = 0; pass < 4; ++pass) {
      const int e = tid * 4 + pass * 1024;   // 4 consecutive [px][ic] elems
      const int e_px = e >> 6, e_ic = e & 63;
      uint2 v1[15], v2[15];
#pragma unroll
      for (int j = 0; j < 15; ++j) {
        v1[j] = *(const uint2*)(cA + bb + (size_t)so1[j] * IMGSZ + e);
        v2[j] = *(const uint2*)(cB + bb + (size_t)so2[j] * IMGSZ + e);
      }
      f32x4 xv = *(const f32x4*)(sXS + e_px * XROW + e_ic);
      float acc[4], br[4];
#pragma unroll
      for (int r = 0; r < 4; ++r) { br[r] = b_rel[e_ic + r]; acc[r] = xv[r]; }
#pragma unroll
      for (int j = 0; j < 15; ++j) {
        float m = sm[j];
        f32x4 a1 = bf4_to_f32(v1[j]);
        f32x4 a2 = bf4_to_f32(v2[j]);
#pragma unroll
        for (int r = 0; r < 4; ++r)
          acc[r] += fmaxf(m * (a1[r] + a2[r]) + br[r], 0.f);
      }
      uint2 pk;
      pk.x = (unsigned)f2bf(acc[0]) | ((unsigned)f2bf(acc[1]) << 16);
      pk.y = (unsigned)f2bf(acc[2]) | ((unsigned)f2bf(acc[3]) << 16);
      *(uint2*)(sPred + e_px * ROW + e_ic) = pk;
    }
  }
  __syncthreads();

  // ---- aff conv: sPred -> a -> sX cols 0..63
  {
    f32x4 f[4] = {};
    const unsigned short* WA = Wt + 36864 + aw64;
#pragma unroll
    for (int tap = 0; tap < 9; ++tap) {
      const int dy = tap / 3 - 1, dx = tap % 3 - 1;
      int spt[4];
#pragma unroll
      for (int t = 0; t < 4; ++t) {
        int sy = pyt[t] + dy, sx = pxt[t] + dx;
        spt[t] = ((unsigned)sy < 8u && (unsigned)sx < 8u) ? (sy * 8 + sx) : 64;
      }
#pragma unroll
      for (int ks = 0; ks < 2; ++ks) {
        bf16x8 a = *(const bf16x8*)(WA + tap * 4096 + ks * 32);
#pragma unroll
        for (int t = 0; t < 4; ++t) {
          bf16x8 bt = *(const bf16x8*)(sPred + spt[t] * ROW + ks * 32 + q * 8);
          f[t] = __builtin_amdgcn_mfma_f32_16x16x32_bf16(a, bt, f[t], 0, 0, 0);
        }
      }
    }
#pragma unroll
    for (int t = 0; t < 4; ++t) {
      int p = t * 16 + n16;
      float v0 = fmaxf(f[t][0] + b_aff[co + 0], 0.f);
      float v1 = fmaxf(f[t][1] + b_aff[co + 1], 0.f);
      float v2 = fmaxf(f[t][2] + b_aff[co + 2], 0.f);
      float v3 = fmaxf(f[t][3] + b_aff[co + 3], 0.f);
      uint2 pk;
      pk.x = (unsigned)f2bf(v0) | ((unsigned)f2bf(v1) << 16);
      pk.y = (unsigned)f2bf(v2) | ((unsigned)f2bf(v3) << 16);
      *(uint2*)(sX + p * ROW2 + co) = pk;
    }
  }
  __syncthreads();

  // ---- agg conv: sX (128 ic: [a|x]) -> out fp32 [ic][px]
  {
    f32x4 g[4] = {};
    const unsigned short* WG = Wt + 147456 + aw128;
#pragma unroll
    for (int tap = 0; tap < 9; ++tap) {
      const int dy = tap / 3 - 1, dx = tap % 3 - 1;
      int spt[4];
#pragma unroll
      for (int t = 0; t < 4; ++t) {
        int sy = pyt[t] + dy, sx = pxt[t] + dx;
        spt[t] = ((unsigned)sy < 8u && (unsigned)sx < 8u) ? (sy * 8 + sx) : 64;
      }
#pragma unroll
      for (int ks = 0; ks < 4; ++ks) {
        bf16x8 a = *(const bf16x8*)(WG + tap * 8192 + ks * 32);
#pragma unroll
        for (int t = 0; t < 4; ++t) {
          bf16x8 bt = *(const bf16x8*)(sX + spt[t] * ROW2 + ks * 32 + q * 8);
          g[t] = __builtin_amdgcn_mfma_f32_16x16x32_bf16(a, bt, g[t], 0, 0, 0);
        }
      }
    }
    float* ob = out + (size_t)img * IMGSZ;
#pragma unroll
    for (int t = 0; t < 4; ++t) {
      int p = t * 16 + n16;
#pragma unroll
      for (int r = 0; r < 4; ++r)
        ob[(co + r) * 64 + p] = fmaxf(g[t][r] + b_agg[co + r], 0.f);
    }
  }
}

extern "C" void kernel_launch(void* const* d_in, const int* in_sizes, int n_in,
                              void* d_out, int out_size, void* d_ws, size_t ws_size,
                              hipStream_t stream) {
  const float* x      = (const float*)d_in[0];
  const int*   g_idx  = (const int*)  d_in[1];
  const float* W_rel  = (const float*)d_in[2];
  const float* b_rel  = (const float*)d_in[3];
  const float* W_self = (const float*)d_in[4];
  const float* b_self = (const float*)d_in[5];
  const float* W_aff  = (const float*)d_in[6];
  const float* b_aff  = (const float*)d_in[7];
  const float* W_agg  = (const float*)d_in[8];
  const float* b_agg  = (const float*)d_in[9];
  float* out = (float*)d_out;

  unsigned short* cA = (unsigned short*)d_ws;      // [512][64][64] bf16
  unsigned short* cB = cA + 2097152;
  unsigned short* Wt = cB + 2097152;               // 221184 bf16

  prep_w<<<864, 256, 0, stream>>>(W_rel, W_self, W_aff, W_agg, Wt);
  k1<<<NIMG, 256, 0, stream>>>(x, Wt, cA, cB);
  k2<<<NIMG, 256, 0, stream>>>(x, g_idx, Wt, b_rel, b_self, b_aff, b_agg,
                               cA, cB, out);
}